// Round 8
// baseline (108.564 us; speedup 1.0000x reference)
//
#include <hip/hip_runtime.h>
#include <hip/hip_bf16.h>

// EmbeddingPredictor: B=16 T=2048 V=32000 E=512 H=4 C=3, f32 in/out.
// R8: shfl-free context via bf16x3 MFMA dots (hi/lo split on BOTH x and P);
//   BM=32, 4-wave blocks, (256,3) -> 3 blocks/CU, grid 1024, no spills.
//   ph0: gather 34 rows f32 -> Xhi LDS bf16 (swizzled)
//   phG: waves 0-2: G[rho][c]=dot(x_rho,P_c) via 3-term MFMA (x re-read f32 from
//        global/L3, hi/lo packed on the fly; P from Pbh/Pbl bf16 pair)
//   phC: per wave 8 tokens: a = sum_c G*x_hi/12 -> regs -> overwrite Xhi rows+2
//   ph2: GEMM rows 0..31 x cols 512 (wave: 128 cols, acc[2][8]), B from L2, no barriers
//   epi: bias + LN (16-lane shfl partials, cross-wave via LDS) + swish -> f32 out
// ws: Pbh @0 (16KB), Pbl @16K (16KB), Wb @32K (512KB).

#define Bq 16
#define Tq 2048
#define Eq 512
#define Cq 3
#define Hq 4
#define Mq (Bq * Tq)
#define LN_EPS 1e-5f

typedef __attribute__((ext_vector_type(8))) short bf16x8;
typedef __attribute__((ext_vector_type(4))) float f32x4;

__device__ __forceinline__ unsigned short f2bf(float f) {
    unsigned int u = __float_as_uint(f);
    u += 0x7fffu + ((u >> 16) & 1u);   // RNE
    return (unsigned short)(u >> 16);
}
__device__ __forceinline__ float bf2f(unsigned short h) {
    return __uint_as_float(((unsigned int)h) << 16);
}
__device__ __forceinline__ unsigned int cvt_pk_bf16(float lo, float hi) {
    unsigned int r;
    asm("v_cvt_pk_bf16_f32 %0, %1, %2" : "=v"(r) : "v"(lo), "v"(hi));
    return r;   // low16 = bf16(lo), high16 = bf16(hi), RNE
}
// swizzled LDS byte address within a [row][1024B] tile
__device__ __forceinline__ int xaddr(int row, int kbyte) {
    return row * 1024 + (kbyte ^ ((row & 7) << 4));
}

// ---------------- K0: prep ----------------
__global__ void prep_kernel(const float* __restrict__ pos,
                            const float* __restrict__ ffn_w,
                            unsigned short* __restrict__ Pbh,  // [16][512] bf16 hi
                            unsigned short* __restrict__ Pbl,  // [16][512] bf16 lo
                            unsigned short* __restrict__ Wb) { // [E][E] bf16
    int i = blockIdx.x * blockDim.x + threadIdx.x;   // 16384 threads
    if (i < 16 * Eq) {
        int c = i / Eq, e = i % Eq;
        float s = 0.f;
        if (c < Cq) {
#pragma unroll
            for (int h = 0; h < Hq; ++h) s += pos[(h * Eq + e) * Cq + c];
        }
        unsigned short hi = f2bf(s);
        Pbh[i] = hi;
        Pbl[i] = f2bf(s - bf2f(hi));
    }
    for (int j = i; j < Eq * Eq; j += 16384) Wb[j] = f2bf(ffn_w[j]);
}

// ---------------- K1: fused ----------------
// grid = M/32 = 1024 blocks, 256 threads (4 waves). Block owns tokens m0..m0+31.
__global__ __launch_bounds__(256, 3) void fused_kernel(const int* __restrict__ tokens,
                                                       const float* __restrict__ tbl,
                                                       const unsigned short* __restrict__ Pbh,
                                                       const unsigned short* __restrict__ Pbl,
                                                       const unsigned short* __restrict__ Wb,
                                                       const float* __restrict__ bias,
                                                       const float* __restrict__ ln_g,
                                                       const float* __restrict__ ln_b,
                                                       float* __restrict__ out) {
    __shared__ __align__(16) unsigned short Xhi[34 * 512];   // 34KB swizzled; rows: X then A(+2)
    __shared__ float Gl[34][4];
    __shared__ float Sm[32][5];
    __shared__ float Sq[32][5];
    __shared__ float lds_mu[32];
    __shared__ float lds_rs[32];

    const int tid = threadIdx.x;
    const int wave = tid >> 6;
    const int lane = tid & 63;
    const int lr = lane & 15;
    const int lg = lane >> 4;
    const int m0 = blockIdx.x << 5;
    const int t0 = m0 & (Tq - 1);
    const int tb = m0 & ~(Tq - 1);
    char* Xc = reinterpret_cast<char*>(Xhi);

    // ---- phase 0: gather rows (wave w: rows w, w+4, ...) -> Xhi bf16 ----
#pragma unroll
    for (int jr = 0; jr < 9; ++jr) {
        const int r = wave + (jr << 2);
        if (r < 34) {
            const int t = t0 + r - 2;
            float4 v0 = {0.f, 0.f, 0.f, 0.f}, v1 = {0.f, 0.f, 0.f, 0.f};
            if (t >= 0) {
                const int tok = tokens[tb + t];
                const float4* rp = reinterpret_cast<const float4*>(tbl + (long)tok * Eq + lane * 8);
                v0 = rp[0]; v1 = rp[1];
            }
            uint4 h;
            h.x = cvt_pk_bf16(v0.x, v0.y);
            h.y = cvt_pk_bf16(v0.z, v0.w);
            h.z = cvt_pk_bf16(v1.x, v1.y);
            h.w = cvt_pk_bf16(v1.z, v1.w);
            *reinterpret_cast<uint4*>(Xc + xaddr(r, lane * 16)) = h;
        }
    }
    __syncthreads();

    // ---- phase G: waves 0..2 compute G[rho][c] via bf16x3 MFMA ----
    if (wave < 3) {
        const int r0 = (wave == 0) ? 0 : (wave == 1) ? 16 : 18;   // rows 18-31 duplicated (benign identical)
        const int trow = t0 + r0 + lr - 2;
        const bool valid = trow >= 0;
        const int tok = valid ? tokens[tb + trow] : 0;
        const float* xrow = tbl + (long)tok * Eq;
        const short* Ph = reinterpret_cast<const short*>(Pbh) + lr * Eq;
        const short* Pl = reinterpret_cast<const short*>(Pbl) + lr * Eq;
        f32x4 g = {0.f, 0.f, 0.f, 0.f};
#pragma unroll
        for (int ks = 0; ks < 16; ++ks) {
            float4 a0 = {0.f, 0.f, 0.f, 0.f}, a1 = {0.f, 0.f, 0.f, 0.f};
            if (valid) {
                const float4* ap = reinterpret_cast<const float4*>(xrow + ks * 32 + lg * 8);
                a0 = ap[0]; a1 = ap[1];
            }
            uint4 hu, lu;
            hu.x = cvt_pk_bf16(a0.x, a0.y);
            hu.y = cvt_pk_bf16(a0.z, a0.w);
            hu.z = cvt_pk_bf16(a1.x, a1.y);
            hu.w = cvt_pk_bf16(a1.z, a1.w);
            lu.x = cvt_pk_bf16(a0.x - __uint_as_float(hu.x << 16), a0.y - __uint_as_float(hu.x & 0xffff0000u));
            lu.y = cvt_pk_bf16(a0.z - __uint_as_float(hu.y << 16), a0.w - __uint_as_float(hu.y & 0xffff0000u));
            lu.z = cvt_pk_bf16(a1.x - __uint_as_float(hu.z << 16), a1.y - __uint_as_float(hu.z & 0xffff0000u));
            lu.w = cvt_pk_bf16(a1.z - __uint_as_float(hu.w << 16), a1.w - __uint_as_float(hu.w & 0xffff0000u));
            const bf16x8 ah = *reinterpret_cast<const bf16x8*>(&hu);
            const bf16x8 al = *reinterpret_cast<const bf16x8*>(&lu);
            const bf16x8 bh = *reinterpret_cast<const bf16x8*>(Ph + ks * 32 + lg * 8);
            const bf16x8 bl = *reinterpret_cast<const bf16x8*>(Pl + ks * 32 + lg * 8);
            g = __builtin_amdgcn_mfma_f32_16x16x32_bf16(ah, bh, g, 0, 0, 0);
            g = __builtin_amdgcn_mfma_f32_16x16x32_bf16(ah, bl, g, 0, 0, 0);
            g = __builtin_amdgcn_mfma_f32_16x16x32_bf16(al, bh, g, 0, 0, 0);
        }
        if (lr < 3) {
#pragma unroll
            for (int i = 0; i < 4; ++i) Gl[r0 + (lg << 2) + i][lr] = g[i];
        }
    }
    __syncthreads();

    // ---- phase C: per wave 8 tokens; combine with x_hi; a-rows held in regs ----
    const int j0 = wave << 3;
    uint4 rr[10];
#pragma unroll
    for (int jj = 0; jj < 10; ++jj)
        rr[jj] = *reinterpret_cast<const uint4*>(Xc + xaddr(j0 + jj, lane * 16));

    const float inv = 1.f / (Hq * Cq);
    uint4 arow[8];
#pragma unroll
    for (int jj = 0; jj < 8; ++jj) {
        const float s0 = Gl[j0 + jj][0] * inv;
        const float s1 = Gl[j0 + jj + 1][1] * inv;
        const float s2 = Gl[j0 + jj + 2][2] * inv;
        float a[8];
#pragma unroll
        for (int e = 0; e < 8; ++e) a[e] = 0.f;
#pragma unroll
        for (int c = 0; c < Cq; ++c) {
            const float sc = (c == 0) ? s0 : (c == 1) ? s1 : s2;
            const uint4 rv = rr[jj + c];
            const unsigned int w0 = rv.x, w1 = rv.y, w2 = rv.z, w3 = rv.w;
            a[0] += sc * __uint_as_float(w0 << 16);
            a[1] += sc * __uint_as_float(w0 & 0xffff0000u);
            a[2] += sc * __uint_as_float(w1 << 16);
            a[3] += sc * __uint_as_float(w1 & 0xffff0000u);
            a[4] += sc * __uint_as_float(w2 << 16);
            a[5] += sc * __uint_as_float(w2 & 0xffff0000u);
            a[6] += sc * __uint_as_float(w3 << 16);
            a[7] += sc * __uint_as_float(w3 & 0xffff0000u);
        }
        uint4 o;
        o.x = cvt_pk_bf16(a[0], a[1]);
        o.y = cvt_pk_bf16(a[2], a[3]);
        o.z = cvt_pk_bf16(a[4], a[5]);
        o.w = cvt_pk_bf16(a[6], a[7]);
        arow[jj] = o;
    }
    __syncthreads();
#pragma unroll
    for (int jj = 0; jj < 8; ++jj)     // A row j stored at Xhi row j+2
        *reinterpret_cast<uint4*>(Xc + xaddr(j0 + jj + 2, lane * 16)) = arow[jj];
    __syncthreads();

    // ---- phase 2: GEMM rows 0..31, wave cols [128w,128w+128), no barriers ----
    const int n0 = wave << 7;
    const short* Bp = reinterpret_cast<const short*>(Wb) + (long)n0 * Eq;

    f32x4 acc[2][8];
#pragma unroll
    for (int i = 0; i < 2; ++i)
#pragma unroll
        for (int j = 0; j < 8; ++j) acc[i][j] = (f32x4){0.f, 0.f, 0.f, 0.f};

#pragma unroll
    for (int kb = 0; kb < 8; ++kb) {
#pragma unroll
        for (int ks = 0; ks < 2; ++ks) {
            bf16x8 af[2], bfv[8];
#pragma unroll
            for (int nf = 0; nf < 8; ++nf)
                bfv[nf] = *reinterpret_cast<const bf16x8*>(Bp + (nf * 16 + lr) * Eq + kb * 64 + ks * 32 + lg * 8);
#pragma unroll
            for (int mf = 0; mf < 2; ++mf)
                af[mf] = *reinterpret_cast<const bf16x8*>(Xc + xaddr(mf * 16 + lr + 2, kb * 128 + ks * 64 + lg * 16));
#pragma unroll
            for (int mf = 0; mf < 2; ++mf)
#pragma unroll
                for (int nf = 0; nf < 8; ++nf)
                    acc[mf][nf] = __builtin_amdgcn_mfma_f32_16x16x32_bf16(af[mf], bfv[nf], acc[mf][nf], 0, 0, 0);
        }
    }

    // ---- epilogue: bias + LayerNorm + swish ----
    float bcol[8];
#pragma unroll
    for (int nf = 0; nf < 8; ++nf) bcol[nf] = bias[n0 + nf * 16 + lr];

#pragma unroll
    for (int mf = 0; mf < 2; ++mf) {
#pragma unroll
        for (int i = 0; i < 4; ++i) {
            float sm = 0.f, sq = 0.f;
#pragma unroll
            for (int nf = 0; nf < 8; ++nf) {
                float v = acc[mf][nf][i] + bcol[nf];
                acc[mf][nf][i] = v;
                sm += v;
                sq += v * v;
            }
#pragma unroll
            for (int msk = 1; msk < 16; msk <<= 1) {
                sm += __shfl_xor(sm, msk, 64);
                sq += __shfl_xor(sq, msk, 64);
            }
            if (lr == 0) {
                const int row = mf * 16 + (lg << 2) + i;
                Sm[row][wave] = sm;
                Sq[row][wave] = sq;
            }
        }
    }
    __syncthreads();
    if (tid < 32) {
        float sm = 0.f, sq = 0.f;
#pragma unroll
        for (int w = 0; w < 4; ++w) { sm += Sm[tid][w]; sq += Sq[tid][w]; }
        const float mu = sm * (1.f / Eq);
        const float var = sq * (1.f / Eq) - mu * mu;
        lds_mu[tid] = mu;
        lds_rs[tid] = rsqrtf(var + LN_EPS);
    }
    __syncthreads();

    float gcol[8], bbcol[8];
#pragma unroll
    for (int nf = 0; nf < 8; ++nf) {
        gcol[nf] = ln_g[n0 + nf * 16 + lr];
        bbcol[nf] = ln_b[n0 + nf * 16 + lr];
    }
#pragma unroll
    for (int mf = 0; mf < 2; ++mf) {
#pragma unroll
        for (int i = 0; i < 4; ++i) {
            const int row = mf * 16 + (lg << 2) + i;
            const float mu = lds_mu[row];
            const float rs = lds_rs[row];
#pragma unroll
            for (int nf = 0; nf < 8; ++nf) {
                float v = acc[mf][nf][i];
                float o = (v - mu) * rs * gcol[nf] + bbcol[nf];
                o = o / (1.f + __expf(-o));   // swish
                out[(long)(m0 + row) * Eq + (n0 + nf * 16 + lr)] = o;
            }
        }
    }
}

extern "C" void kernel_launch(void* const* d_in, const int* in_sizes, int n_in,
                              void* d_out, int out_size, void* d_ws, size_t ws_size,
                              hipStream_t stream) {
    const int* tokens = (const int*)d_in[0];
    const float* tbl = (const float*)d_in[1];
    const float* pos = (const float*)d_in[2];
    const float* ffn_w = (const float*)d_in[3];
    const float* ffn_b = (const float*)d_in[4];
    const float* ln_g = (const float*)d_in[5];
    const float* ln_b = (const float*)d_in[6];
    float* out = (float*)d_out;

    char* ws = (char*)d_ws;
    unsigned short* Pbh = (unsigned short*)ws;               // 16 KB
    unsigned short* Pbl = (unsigned short*)(ws + 16384);     // 16 KB
    unsigned short* Wb = (unsigned short*)(ws + 32768);      // 512 KB

    hipLaunchKernelGGL(prep_kernel, dim3(64), dim3(256), 0, stream, pos, ffn_w, Pbh, Pbl, Wb);
    hipLaunchKernelGGL(fused_kernel, dim3(Mq / 32), dim3(256), 0, stream,
                       tokens, tbl, Pbh, Pbl, Wb, ffn_b, ln_g, ln_b, out);
}

// Round 9
// 86.706 us; speedup vs baseline: 1.2521x; 1.2521x over previous
//
#include <hip/hip_runtime.h>
#include <hip/hip_bf16.h>

// EmbeddingPredictor: B=16 T=2048 V=32000 E=512 H=4 C=3, f32 in/out.
// R9: R5 numerics (f32 dots + shfl, proven absmax 0.031) with BM=32 geometry:
//   512 threads, 8 waves. Wave w: ctx for 4 tokens (rows 4w..4w+3, 6-row halo),
//   GEMM cols [64w,64w+64) over rows 0..31 -> acc[2][4] = 32 AGPR.
//   __launch_bounds__(512,4) caps at 128 regs/wave -> 4 waves/SIMD occupancy.
//   LDS: A-tile 32x512 bf16 swizzled (32KB) + stats ~2KB.
//  K0 prep: Pt[3][512] f32; Wb = bf16(ffn_w)
// ws: Pt @0 (6KB), Wb @8KB (512KB).

#define Bq 16
#define Tq 2048
#define Eq 512
#define Cq 3
#define Hq 4
#define Mq (Bq * Tq)
#define LN_EPS 1e-5f

typedef __attribute__((ext_vector_type(8))) short bf16x8;
typedef __attribute__((ext_vector_type(4))) float f32x4;

__device__ __forceinline__ unsigned short f2bf(float f) {
    unsigned int u = __float_as_uint(f);
    u += 0x7fffu + ((u >> 16) & 1u);   // RNE
    return (unsigned short)(u >> 16);
}
__device__ __forceinline__ unsigned int cvt_pk_bf16(float lo, float hi) {
    unsigned int r;
    asm("v_cvt_pk_bf16_f32 %0, %1, %2" : "=v"(r) : "v"(lo), "v"(hi));
    return r;   // low16 = bf16(lo), high16 = bf16(hi), RNE
}
// swizzled LDS byte address within a [row][1024B] tile
__device__ __forceinline__ int xaddr(int row, int kbyte) {
    return row * 1024 + (kbyte ^ ((row & 7) << 4));
}

// ---------------- K0: prep ----------------
__global__ void prep_kernel(const float* __restrict__ pos,
                            const float* __restrict__ ffn_w,
                            float* __restrict__ Pt,            // [C][E]
                            unsigned short* __restrict__ Wb) { // [E][E] bf16
    int i = blockIdx.x * blockDim.x + threadIdx.x;
    if (i < Cq * Eq) {
        int c = i / Eq, e = i % Eq;
        float s = 0.f;
#pragma unroll
        for (int h = 0; h < Hq; ++h) s += pos[(h * Eq + e) * Cq + c];
        Pt[i] = s;
    }
    int nth = blockDim.x * gridDim.x;
    for (int j = i; j < Eq * Eq; j += nth) Wb[j] = f2bf(ffn_w[j]);
}

// ---------------- K1: fused ctx + FFN GEMM + bias + LayerNorm + swish ----------------
// grid = M/32 = 1024 blocks, 512 threads (8 waves). Block owns tokens m0..m0+31.
// Wave w: ctx tokens m0+4w..m0+4w+3; GEMM cols [64w, 64w+64), rows 0..31.
__global__ __launch_bounds__(512, 4) void fused_kernel(const int* __restrict__ tokens,
                                                       const float* __restrict__ tbl,
                                                       const float* __restrict__ Pt,
                                                       const unsigned short* __restrict__ Wb,
                                                       const float* __restrict__ bias,
                                                       const float* __restrict__ ln_g,
                                                       const float* __restrict__ ln_b,
                                                       float* __restrict__ out) {
    __shared__ __align__(16) unsigned short Atile[32 * 512];   // 32KB, swizzled bf16
    __shared__ float Sm[32][8];
    __shared__ float Sq[32][8];
    __shared__ float lds_mu[32];
    __shared__ float lds_rs[32];

    const int tid = threadIdx.x;
    const int wave = tid >> 6;
    const int lane = tid & 63;
    const int lr = lane & 15;
    const int lg = lane >> 4;
    const int m0 = blockIdx.x << 5;
    const int t0w = (m0 & (Tq - 1)) + (wave << 2);
    const int tb = m0 & ~(Tq - 1);
    char* Xc = reinterpret_cast<char*>(Atile);

    const int n0 = wave << 6;
    const short* Bp = reinterpret_cast<const short*>(Wb) + (long)n0 * Eq;

    // ---- phase 1a: gather 6 rows (4 tokens + 2 halo) in f32 regs ----
    float x[6][8];
#pragma unroll
    for (int li = 0; li < 6; ++li) {
        const int t = t0w - 2 + li;
        float4 v0 = {0.f, 0.f, 0.f, 0.f}, v1 = {0.f, 0.f, 0.f, 0.f};
        if (t >= 0) {
            const int tok = tokens[tb + t];
            const float4* rp = reinterpret_cast<const float4*>(tbl + (long)tok * Eq + lane * 8);
            v0 = rp[0]; v1 = rp[1];
        }
        x[li][0] = v0.x; x[li][1] = v0.y; x[li][2] = v0.z; x[li][3] = v0.w;
        x[li][4] = v1.x; x[li][5] = v1.y; x[li][6] = v1.z; x[li][7] = v1.w;
    }

    // ---- phase 1b: f32 dots (valid iff 0 <= li-c <= 3) + wave reduce ----
    float d[6][Cq];
#pragma unroll
    for (int c = 0; c < Cq; ++c) {
        const float4* pp = reinterpret_cast<const float4*>(Pt + c * Eq + lane * 8);
        const float4 p0 = pp[0], p1 = pp[1];
#pragma unroll
        for (int li = 0; li < 6; ++li) {
            if (li >= c && li - c <= 3) {
                d[li][c] = x[li][0] * p0.x + x[li][1] * p0.y + x[li][2] * p0.z + x[li][3] * p0.w
                         + x[li][4] * p1.x + x[li][5] * p1.y + x[li][6] * p1.z + x[li][7] * p1.w;
            }
        }
    }
#pragma unroll
    for (int li = 0; li < 6; ++li)
#pragma unroll
        for (int c = 0; c < Cq; ++c)
            if (li >= c && li - c <= 3) {
#pragma unroll
                for (int m = 1; m < 64; m <<= 1) d[li][c] += __shfl_xor(d[li][c], m, 64);
            }

    // ---- phase 1c: combination -> cvt_pk -> swizzled LDS A-tile (rows 4w..4w+3) ----
    const float inv = 1.f / (Hq * Cq);
#pragma unroll
    for (int jj = 0; jj < 4; ++jj) {
        const float s0 = d[jj][0] * inv, s1 = d[jj + 1][1] * inv, s2 = d[jj + 2][2] * inv;
        float a[8];
#pragma unroll
        for (int e = 0; e < 8; ++e)
            a[e] = s0 * x[jj][e] + s1 * x[jj + 1][e] + s2 * x[jj + 2][e];
        uint4 o;
        o.x = cvt_pk_bf16(a[0], a[1]);
        o.y = cvt_pk_bf16(a[2], a[3]);
        o.z = cvt_pk_bf16(a[4], a[5]);
        o.w = cvt_pk_bf16(a[6], a[7]);
        const int row = (wave << 2) + jj;
        *reinterpret_cast<uint4*>(Xc + xaddr(row, lane * 16)) = o;
    }
    __syncthreads();

    // ---- phase 2: GEMM, no inner barriers; A (32 rows) from LDS, B (64 cols) from L2 ----
    f32x4 acc[2][4];
#pragma unroll
    for (int i = 0; i < 2; ++i)
#pragma unroll
        for (int j = 0; j < 4; ++j) acc[i][j] = (f32x4){0.f, 0.f, 0.f, 0.f};

#pragma unroll
    for (int kb = 0; kb < 8; ++kb) {
#pragma unroll
        for (int ks = 0; ks < 2; ++ks) {
            bf16x8 af[2], bfv[4];
#pragma unroll
            for (int nf = 0; nf < 4; ++nf)
                bfv[nf] = *reinterpret_cast<const bf16x8*>(Bp + (nf * 16 + lr) * Eq + kb * 64 + ks * 32 + lg * 8);
#pragma unroll
            for (int mf = 0; mf < 2; ++mf)
                af[mf] = *reinterpret_cast<const bf16x8*>(Xc + xaddr(mf * 16 + lr, kb * 128 + ks * 64 + lg * 16));
#pragma unroll
            for (int mf = 0; mf < 2; ++mf)
#pragma unroll
                for (int nf = 0; nf < 4; ++nf)
                    acc[mf][nf] = __builtin_amdgcn_mfma_f32_16x16x32_bf16(af[mf], bfv[nf], acc[mf][nf], 0, 0, 0);
        }
    }

    // ---- epilogue: bias + LayerNorm + swish ----
    float bcol[4];
#pragma unroll
    for (int nf = 0; nf < 4; ++nf) bcol[nf] = bias[n0 + nf * 16 + lr];

#pragma unroll
    for (int mf = 0; mf < 2; ++mf) {
#pragma unroll
        for (int i = 0; i < 4; ++i) {
            float sm = 0.f, sq = 0.f;
#pragma unroll
            for (int nf = 0; nf < 4; ++nf) {
                float v = acc[mf][nf][i] + bcol[nf];
                acc[mf][nf][i] = v;
                sm += v;
                sq += v * v;
            }
#pragma unroll
            for (int msk = 1; msk < 16; msk <<= 1) {
                sm += __shfl_xor(sm, msk, 64);
                sq += __shfl_xor(sq, msk, 64);
            }
            if (lr == 0) {
                const int row = mf * 16 + (lg << 2) + i;
                Sm[row][wave] = sm;
                Sq[row][wave] = sq;
            }
        }
    }
    __syncthreads();
    if (tid < 32) {
        float sm = 0.f, sq = 0.f;
#pragma unroll
        for (int w = 0; w < 8; ++w) { sm += Sm[tid][w]; sq += Sq[tid][w]; }
        const float mu = sm * (1.f / Eq);
        const float var = sq * (1.f / Eq) - mu * mu;
        lds_mu[tid] = mu;
        lds_rs[tid] = rsqrtf(var + LN_EPS);
    }
    __syncthreads();

    float gcol[4], bbcol[4];
#pragma unroll
    for (int nf = 0; nf < 4; ++nf) {
        gcol[nf] = ln_g[n0 + nf * 16 + lr];
        bbcol[nf] = ln_b[n0 + nf * 16 + lr];
    }
#pragma unroll
    for (int mf = 0; mf < 2; ++mf) {
#pragma unroll
        for (int i = 0; i < 4; ++i) {
            const int row = mf * 16 + (lg << 2) + i;
            const float mu = lds_mu[row];
            const float rs = lds_rs[row];
#pragma unroll
            for (int nf = 0; nf < 4; ++nf) {
                float v = acc[mf][nf][i];
                float o = (v - mu) * rs * gcol[nf] + bbcol[nf];
                o = o / (1.f + __expf(-o));   // swish
                out[(long)(m0 + row) * Eq + (n0 + nf * 16 + lr)] = o;
            }
        }
    }
}

extern "C" void kernel_launch(void* const* d_in, const int* in_sizes, int n_in,
                              void* d_out, int out_size, void* d_ws, size_t ws_size,
                              hipStream_t stream) {
    const int* tokens = (const int*)d_in[0];
    const float* tbl = (const float*)d_in[1];
    const float* pos = (const float*)d_in[2];
    const float* ffn_w = (const float*)d_in[3];
    const float* ffn_b = (const float*)d_in[4];
    const float* ln_g = (const float*)d_in[5];
    const float* ln_b = (const float*)d_in[6];
    float* out = (float*)d_out;

    char* ws = (char*)d_ws;
    float* Pt = (float*)ws;                              // 6 KB
    unsigned short* Wb = (unsigned short*)(ws + 8192);   // 512 KB

    hipLaunchKernelGGL(prep_kernel, dim3(64), dim3(256), 0, stream, pos, ffn_w, Pt, Wb);
    hipLaunchKernelGGL(fused_kernel, dim3(Mq / 32), dim3(512), 0, stream,
                       tokens, tbl, Pt, Wb, ffn_b, ln_g, ln_b, out);
}

// Round 10
// 75.218 us; speedup vs baseline: 1.4433x; 1.1527x over previous
//
#include <hip/hip_runtime.h>
#include <hip/hip_bf16.h>

// EmbeddingPredictor: B=16 T=2048 V=32000 E=512 H=4 C=3, f32 in/out.
// R10: de-fused, latency-structured FFN.
//  K0 prep: Pt[3][512] f32; Wb = bf16(ffn_w) [n][k].
//  K1 ctx (R1 proven, absmax 0.031): wave-per-token; writes out1 as the
//     xaddr-SWIZZLED 64KB-per-64-row-tile image (so K2's linear global_load_lds
//     reproduces the swizzled LDS layout — swizzle on both sides).
//  K2 ffn: per block (64 rows, full N=512): A staged once via global_load_lds
//     (8 rounds/wave, cooperative); B streamed in BK=32 chunks, double-buffered,
//     PER-WAVE-PRIVATE slabs (wave w owns cols 64w..64w+63 = B rows 64w..),
//     counted vmcnt(4), ZERO barriers in the K-loop. MFMA 16x16x32, acc[4][4].
//     Epilogue: bias + LayerNorm + swish (proven).
// ws: Pt @0 (6KB), Wb @8KB (512KB), out1 @1MB (32MB swizzled image).

#define Bq 16
#define Tq 2048
#define Eq 512
#define Cq 3
#define Hq 4
#define Mq (Bq * Tq)
#define LN_EPS 1e-5f

typedef __attribute__((ext_vector_type(8))) short bf16x8;
typedef __attribute__((ext_vector_type(4))) float f32x4;

__device__ __forceinline__ unsigned int cvt_pk_bf16(float lo, float hi) {
    unsigned int r;
    asm("v_cvt_pk_bf16_f32 %0, %1, %2" : "=v"(r) : "v"(lo), "v"(hi));
    return r;   // low16 = bf16(lo), high16 = bf16(hi), RNE
}
__device__ __forceinline__ unsigned short f2bf(float f) {
    unsigned int u = __float_as_uint(f);
    u += 0x7fffu + ((u >> 16) & 1u);   // RNE
    return (unsigned short)(u >> 16);
}
// swizzled byte address within a [row][1024B] tile (A-tile swizzle)
__device__ __forceinline__ int xaddr(int row, int kbyte) {
    return row * 1024 + (kbyte ^ ((row & 7) << 4));
}

// ---------------- K0: prep ----------------
__global__ void prep_kernel(const float* __restrict__ pos,
                            const float* __restrict__ ffn_w,
                            float* __restrict__ Pt,            // [C][E]
                            unsigned short* __restrict__ Wb) { // [E][E] bf16 [n][k]
    int i = blockIdx.x * blockDim.x + threadIdx.x;
    if (i < Cq * Eq) {
        int c = i / Eq, e = i % Eq;
        float s = 0.f;
#pragma unroll
        for (int h = 0; h < Hq; ++h) s += pos[(h * Eq + e) * Cq + c];
        Pt[i] = s;
    }
    int nth = blockDim.x * gridDim.x;
    for (int j = i; j < Eq * Eq; j += nth) Wb[j] = f2bf(ffn_w[j]);
}

// ---------------- K1: context (R1 structure, swizzled store) ----------------
// one wave per token; 4 tokens per 256-thread block; grid = M/4
__global__ __launch_bounds__(256) void ctx_kernel(const int* __restrict__ tokens,
                                                  const float* __restrict__ tbl,
                                                  const float* __restrict__ Pt,
                                                  char* __restrict__ out1) {
    const int wave = threadIdx.x >> 6;
    const int lane = threadIdx.x & 63;
    const int tt = blockIdx.x * 4 + wave;   // 0..M-1
    const int b = tt >> 11;                 // T = 2048
    const int t = tt & (Tq - 1);

    float x[Cq][8];
    float s[Cq];
#pragma unroll
    for (int c = 0; c < Cq; ++c) {
        const int r = t - (Cq - 1) + c;
        if (r >= 0) {
            const int tok = tokens[(b << 11) + r];
            const float4* row = reinterpret_cast<const float4*>(tbl + (long)tok * Eq + lane * 8);
            float4 v0 = row[0], v1 = row[1];
            x[c][0] = v0.x; x[c][1] = v0.y; x[c][2] = v0.z; x[c][3] = v0.w;
            x[c][4] = v1.x; x[c][5] = v1.y; x[c][6] = v1.z; x[c][7] = v1.w;
        } else {
#pragma unroll
            for (int j = 0; j < 8; ++j) x[c][j] = 0.f;
        }
        const float4* pp = reinterpret_cast<const float4*>(Pt + c * Eq + lane * 8);
        float4 p0 = pp[0], p1 = pp[1];
        s[c] = x[c][0] * p0.x + x[c][1] * p0.y + x[c][2] * p0.z + x[c][3] * p0.w
             + x[c][4] * p1.x + x[c][5] * p1.y + x[c][6] * p1.z + x[c][7] * p1.w;
    }
#pragma unroll
    for (int m = 1; m < 64; m <<= 1) {
        s[0] += __shfl_xor(s[0], m, 64);
        s[1] += __shfl_xor(s[1], m, 64);
        s[2] += __shfl_xor(s[2], m, 64);
    }
    const float inv = 1.f / (Hq * Cq);
    float a[8];
#pragma unroll
    for (int j = 0; j < 8; ++j)
        a[j] = (s[0] * x[0][j] + s[1] * x[1][j] + s[2] * x[2][j]) * inv;
    uint4 o;
    o.x = cvt_pk_bf16(a[0], a[1]);
    o.y = cvt_pk_bf16(a[2], a[3]);
    o.z = cvt_pk_bf16(a[4], a[5]);
    o.w = cvt_pk_bf16(a[6], a[7]);
    // swizzled image: tile = tt>>6 (64KB each), row = tt&63
    char* dst = out1 + ((long)(tt >> 6) << 16) + xaddr(tt & 63, lane * 16);
    *reinterpret_cast<uint4*>(dst) = o;
}

// ---------------- K2: FFN GEMM + bias + LayerNorm + swish ----------------
// grid = M/64 = 512 blocks, 512 threads (8 waves). Block rows m0..m0+63, full N.
// Wave w: cols [64w, 64w+64); private B slab (2 bufs x 4KB) in LDS; no K-loop barriers.
__global__ __launch_bounds__(512, 2) void ffn_kernel(const char* __restrict__ A1,
                                                     const unsigned short* __restrict__ Wb,
                                                     const float* __restrict__ bias,
                                                     const float* __restrict__ ln_g,
                                                     const float* __restrict__ ln_b,
                                                     float* __restrict__ out) {
    __shared__ __align__(16) char Alds[65536];   // swizzled A image, 64 rows x 1KB
    __shared__ __align__(16) char Blds[65536];   // 8 waves x (2 x 4KB chunk bufs)
    __shared__ float Sm[64][8];
    __shared__ float Sq[64][8];
    __shared__ float lds_mu[64];
    __shared__ float lds_rs[64];

    const int tid = threadIdx.x;
    const int wave = tid >> 6;
    const int lane = tid & 63;
    const int lr = lane & 15;
    const int lg = lane >> 4;
    const int m0 = blockIdx.x << 6;
    const int n0 = wave << 6;

    const char* Asrc = A1 + ((long)blockIdx.x << 16);
    const char* WbB = reinterpret_cast<const char*>(Wb);
    char* Bw = Blds + wave * 8192;

    // lane's fixed B-stage geometry: covers row rn = q*16 + (lane>>2), slot s = lane&3
    const int rn_base = lane >> 2;        // + q*16
    const int s_slot = lane & 3;

    // ---- prologue: stage A (8 rounds/wave, cooperative) + B chunks 0,1 ----
#pragma unroll
    for (int q = 0; q < 8; ++q) {
        __builtin_amdgcn_global_load_lds(
            (const __attribute__((address_space(1))) void*)(Asrc + wave * 8192 + q * 1024 + lane * 16),
            (__attribute__((address_space(3))) void*)(Alds + wave * 8192 + q * 1024), 16, 0, 0);
    }
#pragma unroll
    for (int kc0 = 0; kc0 < 2; ++kc0) {
#pragma unroll
        for (int q = 0; q < 4; ++q) {
            const int rn = q * 16 + rn_base;
            const int n = n0 + rn;
            const int gb = n * 1024 + kc0 * 64 + ((s_slot * 16) ^ ((n & 3) << 4));
            __builtin_amdgcn_global_load_lds(
                (const __attribute__((address_space(1))) void*)(WbB + gb),
                (__attribute__((address_space(3))) void*)(Bw + kc0 * 4096 + q * 1024), 16, 0, 0);
        }
    }
    asm volatile("s_waitcnt vmcnt(8)" ::: "memory");   // own A rounds done (B0,B1 in flight)
    __syncthreads();                                    // => all waves' A rounds done

    // ---- K-loop: 16 chunks of BK=32, double-buffered private B, no barriers ----
    f32x4 acc[4][4];
#pragma unroll
    for (int i = 0; i < 4; ++i)
#pragma unroll
        for (int j = 0; j < 4; ++j) acc[i][j] = (f32x4){0.f, 0.f, 0.f, 0.f};

#pragma unroll
    for (int kc = 0; kc < 16; ++kc) {
        const int buf = (kc & 1) * 4096;
        bf16x8 af[4], bfv[4];
#pragma unroll
        for (int mf = 0; mf < 4; ++mf)
            af[mf] = *reinterpret_cast<const bf16x8*>(Alds + xaddr(mf * 16 + lr, kc * 64 + lg * 16));
#pragma unroll
        for (int nf = 0; nf < 4; ++nf) {
            const int rn = nf * 16 + lr;
            bfv[nf] = *reinterpret_cast<const bf16x8*>(Bw + buf + rn * 64 + ((lg * 16) ^ ((rn & 3) << 4)));
        }
        if (kc < 14) {
            // reads of this buf must be in-flight-complete before overwrite
            asm volatile("s_waitcnt lgkmcnt(0)" ::: "memory");
            const int kn = kc + 2;
#pragma unroll
            for (int q = 0; q < 4; ++q) {
                const int rn = q * 16 + rn_base;
                const int n = n0 + rn;
                const int gb = n * 1024 + kn * 64 + ((s_slot * 16) ^ ((n & 3) << 4));
                __builtin_amdgcn_global_load_lds(
                    (const __attribute__((address_space(1))) void*)(WbB + gb),
                    (__attribute__((address_space(3))) void*)(Bw + buf + q * 1024), 16, 0, 0);
            }
        }
#pragma unroll
        for (int mf = 0; mf < 4; ++mf)
#pragma unroll
            for (int nf = 0; nf < 4; ++nf)
                acc[mf][nf] = __builtin_amdgcn_mfma_f32_16x16x32_bf16(af[mf], bfv[nf], acc[mf][nf], 0, 0, 0);
        if (kc < 14)       asm volatile("s_waitcnt vmcnt(4)" ::: "memory");   // chunk kc+1 landed
        else if (kc == 14) asm volatile("s_waitcnt vmcnt(0)" ::: "memory");   // chunk 15 landed
    }

    // ---- epilogue: bias + LayerNorm + swish ----
    float bcol[4];
#pragma unroll
    for (int nf = 0; nf < 4; ++nf) bcol[nf] = bias[n0 + nf * 16 + lr];

#pragma unroll
    for (int mf = 0; mf < 4; ++mf) {
#pragma unroll
        for (int i = 0; i < 4; ++i) {
            float sm = 0.f, sq = 0.f;
#pragma unroll
            for (int nf = 0; nf < 4; ++nf) {
                float v = acc[mf][nf][i] + bcol[nf];
                acc[mf][nf][i] = v;
                sm += v;
                sq += v * v;
            }
#pragma unroll
            for (int msk = 1; msk < 16; msk <<= 1) {
                sm += __shfl_xor(sm, msk, 64);
                sq += __shfl_xor(sq, msk, 64);
            }
            if (lr == 0) {
                const int row = mf * 16 + (lg << 2) + i;
                Sm[row][wave] = sm;
                Sq[row][wave] = sq;
            }
        }
    }
    __syncthreads();
    if (tid < 64) {
        float sm = 0.f, sq = 0.f;
#pragma unroll
        for (int w = 0; w < 8; ++w) { sm += Sm[tid][w]; sq += Sq[tid][w]; }
        const float mu = sm * (1.f / Eq);
        const float var = sq * (1.f / Eq) - mu * mu;
        lds_mu[tid] = mu;
        lds_rs[tid] = rsqrtf(var + LN_EPS);
    }
    __syncthreads();

    float gcol[4], bbcol[4];
#pragma unroll
    for (int nf = 0; nf < 4; ++nf) {
        gcol[nf] = ln_g[n0 + nf * 16 + lr];
        bbcol[nf] = ln_b[n0 + nf * 16 + lr];
    }
#pragma unroll
    for (int mf = 0; mf < 4; ++mf) {
#pragma unroll
        for (int i = 0; i < 4; ++i) {
            const int row = mf * 16 + (lg << 2) + i;
            const float mu = lds_mu[row];
            const float rs = lds_rs[row];
#pragma unroll
            for (int nf = 0; nf < 4; ++nf) {
                float v = acc[mf][nf][i];
                float o = (v - mu) * rs * gcol[nf] + bbcol[nf];
                o = o / (1.f + __expf(-o));   // swish
                out[(long)(m0 + row) * Eq + (n0 + nf * 16 + lr)] = o;
            }
        }
    }
}

extern "C" void kernel_launch(void* const* d_in, const int* in_sizes, int n_in,
                              void* d_out, int out_size, void* d_ws, size_t ws_size,
                              hipStream_t stream) {
    const int* tokens = (const int*)d_in[0];
    const float* tbl = (const float*)d_in[1];
    const float* pos = (const float*)d_in[2];
    const float* ffn_w = (const float*)d_in[3];
    const float* ffn_b = (const float*)d_in[4];
    const float* ln_g = (const float*)d_in[5];
    const float* ln_b = (const float*)d_in[6];
    float* out = (float*)d_out;

    char* ws = (char*)d_ws;
    float* Pt = (float*)ws;                              // 6 KB
    unsigned short* Wb = (unsigned short*)(ws + 8192);   // 512 KB
    char* out1 = ws + (1 << 20);                         // 32 MB swizzled image

    hipLaunchKernelGGL(prep_kernel, dim3(64), dim3(256), 0, stream, pos, ffn_w, Pt, Wb);
    hipLaunchKernelGGL(ctx_kernel, dim3(Mq / 4), dim3(256), 0, stream, tokens, tbl, Pt, out1);
    hipLaunchKernelGGL(ffn_kernel, dim3(Mq / 64), dim3(512), 0, stream,
                       out1, Wb, ffn_b, ln_g, ln_b, out);
}